// Round 3
// baseline (268.490 us; speedup 1.0000x reference)
//
#include <hip/hip_runtime.h>
#include <cstdint>
#include <cstddef>

#define BB 4
#define NN 16384
#define PRE 4096
#define POST 512
#define CAP 32
#define SELCAP 8192

typedef unsigned short u16;
typedef unsigned int u32;
typedef unsigned long long u64;

// monotone map: f32 bits -> u32 ordinal preserving float order
__device__ __forceinline__ u32 ord32(float f) {
  u32 u = __builtin_bit_cast(u32, f);
  return (u & 0x80000000u) ? ~u : (u | 0x80000000u);
}

// ---------------- K0: per-batch histogram of top-14 ordinal bits ----------------
__global__ void hist_kernel(const float* __restrict__ cls, u32* __restrict__ hist) {
  int g = blockIdx.x * 256 + threadIdx.x;
  if (g >= BB * NN) return;
  int b = g >> 14;
  const float* c = cls + (size_t)g * 3;
  float s = fmaxf(fmaxf(c[0], c[1]), c[2]);
  u32 o = ord32(s);
  atomicAdd(&hist[(b << 14) + (o >> 18)], 1u);
}

// ---------------- K1a: find threshold bin B* (rank-PRE crossing, descending) ----------------
__global__ __launch_bounds__(1024) void bstar_kernel(const u32* __restrict__ hist,
                                                     u32* __restrict__ bstar) {
  __shared__ u32 orig[1024];
  __shared__ u32 bufA[1024];
  __shared__ u32 bufB[1024];
  __shared__ int bs;
  int b = blockIdx.x, t = threadIdx.x;
  const u32* h = hist + (b << 14);
  u32 s = 0;
#pragma unroll
  for (int j = 0; j < 16; ++j) s += h[t * 16 + j];
  orig[t] = s;
  bufA[t] = s;
  if (t == 0) bs = 0;
  __syncthreads();
  // inclusive suffix scan over 1024 chunk totals (Hillis-Steele, double buffer)
  u32* src = bufA;
  u32* dst = bufB;
  for (int off = 1; off < 1024; off <<= 1) {
    u32 v = src[t] + ((t + off < 1024) ? src[t + off] : 0u);
    dst[t] = v;
    __syncthreads();
    u32* tmp = src; src = dst; dst = tmp;
  }
  u32 running = src[t] - orig[t];  // suffix of all bins above this chunk
  for (int j = 15; j >= 0; --j) {
    u32 v = h[t * 16 + j];
    u32 nr = running + v;
    if (nr >= (u32)PRE && running < (u32)PRE) bs = t * 16 + j;  // unique crossing
    running = nr;
  }
  __syncthreads();
  if (t == 0) bstar[b] = (u32)bs;
}

// ---------------- K1b: select candidates (bin >= B*), bitonic sort 8192 u64, emit top-4096 ----------------
__global__ __launch_bounds__(1024) void select_kernel(const float* __restrict__ cls,
                                                      const u32* __restrict__ bstar,
                                                      u32* __restrict__ selctr,
                                                      u32* __restrict__ sidx) {
  __shared__ u64 sk[SELCAP];  // exactly 64 KB
  int b = blockIdx.x, t = threadIdx.x;
  for (int p = t; p < SELCAP; p += 1024) sk[p] = 0ull;  // pad keys sort to the end
  __syncthreads();
  const float* c = cls + ((size_t)(b << 14)) * 3;
  u32 B = bstar[b];
  for (int n = t; n < NN; n += 1024) {
    float s = fmaxf(fmaxf(c[n * 3], c[n * 3 + 1]), c[n * 3 + 2]);
    u32 o = ord32(s);
    if ((o >> 18) >= B) {
      u32 pos = atomicAdd(&selctr[b], 1u);
      if (pos < SELCAP) sk[pos] = ((u64)o << 14) | (u64)(NN - 1 - n);  // score desc, idx asc
    }
  }
  __syncthreads();
  for (int k = 2; k <= SELCAP; k <<= 1) {
    for (int j = k >> 1; j > 0; j >>= 1) {
      for (int s2 = t; s2 < SELCAP / 2; s2 += 1024) {
        int low = s2 & (j - 1);
        int i = ((s2 ^ low) << 1) | low;
        int ixj = i | j;
        u64 a = sk[i], d = sk[ixj];
        bool desc = ((i & k) == 0);
        bool sw = desc ? (a < d) : (a > d);
        if (sw) { sk[i] = d; sk[ixj] = a; }
      }
      __syncthreads();
    }
  }
  for (int p = t; p < PRE; p += 1024)
    sidx[(b << 12) + p] = (u32)(NN - 1) - (u32)(sk[p] & 0x3FFFull);
}

// ---------------- K2: gather geometry / scores / labels for top-4096 ----------------
__global__ void geom_kernel(const float* __restrict__ box, const float* __restrict__ cls,
                            const u32* __restrict__ sidx,
                            float* __restrict__ gx1, float* __restrict__ gx2,
                            float* __restrict__ gy1, float* __restrict__ gy2,
                            float* __restrict__ garea, float* __restrict__ gsc,
                            u32* __restrict__ glab, u32* __restrict__ cnt,
                            u64* __restrict__ hasadj) {
  int g = blockIdx.x * 256 + threadIdx.x;
  if (g >= BB * PRE) return;
  int b = g >> 12;
  u32 idx = sidx[g];
  const float* bp = box + ((size_t)(b << 14) + idx) * 7;
  float x = bp[0], y = bp[1];
  float dx = bp[3], dy = bp[4];
  gx1[g] = x - dx * 0.5f;
  gx2[g] = x + dx * 0.5f;
  gy1[g] = y - dy * 0.5f;
  gy2[g] = y + dy * 0.5f;
  garea[g] = dx * dy;
  const float* cp = cls + ((size_t)(b << 14) + idx) * 3;
  float f0 = cp[0], f1 = cp[1], f2 = cp[2];
  int lab = 0;
  float best = f0;
  if (f1 > best) { best = f1; lab = 1; }
  if (f2 > best) { best = f2; lab = 2; }
  gsc[g] = best;
  glab[g] = (u32)lab;
  cnt[g] = 0;
  if ((g & 4095) < 64) hasadj[(b << 6) + (g & 63)] = 0ull;
}

// ---------------- K3: sparse suppression graph (i<j pairs with IoU>0.8) ----------------
__global__ void pairs_kernel(const float* __restrict__ gx1, const float* __restrict__ gx2,
                             const float* __restrict__ gy1, const float* __restrict__ gy2,
                             const float* __restrict__ garea,
                             u32* __restrict__ cnt, u32* __restrict__ adj,
                             u64* __restrict__ hasadj) {
  int bid = blockIdx.x;
  int b = bid >> 12;
  int r = bid & 4095;
  int ti = r >> 6, tj = r & 63;
  if (tj < ti) return;  // upper triangle of 64x64 tiles only
  int tid = threadIdx.x;
#pragma unroll
  for (int m = 0; m < 16; ++m) {
    int pid = tid + 256 * m;
    int il = pid >> 6, jl = pid & 63;
    int i = ti * 64 + il, j = tj * 64 + jl;
    if (j <= i) continue;
    int gi = (b << 12) + i, gj = (b << 12) + j;
    float ix = fminf(gx2[gi], gx2[gj]) - fmaxf(gx1[gi], gx1[gj]);
    ix = fmaxf(ix, 0.0f);
    float iy = fminf(gy2[gi], gy2[gj]) - fmaxf(gy1[gi], gy1[gj]);
    iy = fmaxf(iy, 0.0f);
    float inter = ix * iy;
    float denom = ((garea[gi] + garea[gj]) - inter) + 1e-6f;  // np op order
    float iou = inter / denom;                                // IEEE f32 div
    if (iou > 0.8f) {
      u32 pos = atomicAdd(&cnt[gi], 1u);
      if (pos < CAP) adj[(size_t)gi * CAP + pos] = (u32)j;
      if (pos == 0u) atomicOr(&hasadj[(b << 6) + (i >> 6)], 1ull << (i & 63));
    }
  }
}

// ---------------- K4: sequential NMS scan (lane 0) + all outputs (FLOAT32 out) ----------------
__global__ __launch_bounds__(256) void nms_kernel(
    const float* __restrict__ box, const float* __restrict__ gt,
    const u32* __restrict__ sidx, const float* __restrict__ gsc,
    const u32* __restrict__ glab, const u32* __restrict__ cnt,
    const u32* __restrict__ adj, const u64* __restrict__ hasadj,
    float* __restrict__ out) {
  __shared__ u64 sval[64];
  __shared__ u64 shadj[64];
  __shared__ u16 ssel[POST];
  __shared__ u16 skeep[POST];
  const int b = blockIdx.x, tid = threadIdx.x;
  if (tid < 64) {
    sval[tid] = ~0ull;
    shadj[tid] = hasadj[(b << 6) + tid];
  }
  __syncthreads();
  if (tid == 0) {
    int t = 0, wi = 0;
    u64 cw = sval[0], ha = shadj[0];
    while (t < POST) {
      if (cw == 0ull) {
        ++wi;
        if (wi == 64) break;
        cw = sval[wi];
        ha = shadj[wi];
        continue;
      }
      int bit = __ffsll((unsigned long long)cw) - 1;
      cw &= cw - 1;  // consume lowest set bit (= argmax(valid))
      int i = (wi << 6) + bit;
      ssel[t] = (u16)i;
      skeep[t] = 1;
      if ((ha >> bit) & 1ull) {  // rare: this box suppresses someone
        int c = (int)cnt[(b << 12) + i];
        if (c > CAP) c = CAP;
        for (int k2 = 0; k2 < c; ++k2) {
          u32 j = adj[((size_t)((b << 12) + i)) * CAP + k2];  // all j > i, j < 4096
          int wj = (int)(j >> 6);
          u64 mask = ~(1ull << (j & 63u));
          if (wj == wi) cw &= mask;
          else sval[wj] &= mask;
        }
      }
      ++t;
    }
    for (; t < POST; ++t) { ssel[t] = 0; skeep[t] = 0; }
  }
  __syncthreads();

  float* rois = out;                  // B*POST*7
  float* rsc  = out + BB * POST * 7;  // B*POST
  float* rlb  = rsc + BB * POST;      // B*POST
  float* rct  = rlb + BB * POST;      // B*POST*8

  const float TWO_PI_F = 6.283185307179586f;
  const float PI_F = 3.14159265358979323846f;
  const float HALF_PI_F = 1.5707963267948966f;
  const float THREE_HALF_PI_F = 4.71238898038469f;

  for (int t = tid; t < POST; t += 256) {
    int i = ssel[t];
    int kp = skeep[t];
    int g = (b << 12) + i;
    u32 idx = sidx[g];
    const float* bp = box + ((size_t)(b << 14) + idx) * 7;
    float bx[7];
#pragma unroll
    for (int d = 0; d < 7; ++d) bx[d] = kp ? bp[d] : 0.0f;
    float* ro = rois + ((size_t)b * POST + t) * 7;
#pragma unroll
    for (int d = 0; d < 7; ++d) ro[d] = bx[d];
    rsc[b * POST + t] = kp ? gsc[g] : 0.0f;
    rlb[b * POST + t] = (float)((kp ? (int)glab[g] : 0) + 1);

    // canonical transform in f32, matching np op order
    const float* gp = gt + ((size_t)b * POST + t) * 8;
    float g0 = gp[0], g1 = gp[1], g2 = gp[2], g6 = gp[6];
    float rr = fmodf(bx[6], TWO_PI_F);
    if (rr < 0.0f) rr += TWO_PI_F;
    float xyz0 = g0 - bx[0], xyz1 = g1 - bx[1], xyz2 = g2 - bx[2];
    float heading = g6 - rr;
    float aa = -rr;
    float cc = cosf(aa), s2 = sinf(aa);
    float nx = xyz0 * cc - xyz1 * s2;
    float ny = xyz0 * s2 + xyz1 * cc;
    float h = fmodf(heading, TWO_PI_F);
    if (h < 0.0f) h += TWO_PI_F;
    bool opp = (h > HALF_PI_F) && (h < THREE_HALF_PI_F);
    if (opp) {
      h = fmodf(h + PI_F, TWO_PI_F);
      if (h < 0.0f) h += TWO_PI_F;
    }
    if (h > PI_F) h -= TWO_PI_F;
    h = fminf(fmaxf(h, -HALF_PI_F), HALF_PI_F);

    float* co = rct + ((size_t)b * POST + t) * 8;
    co[0] = nx;
    co[1] = ny;
    co[2] = xyz2;
    co[3] = gp[3];
    co[4] = gp[4];
    co[5] = gp[5];
    co[6] = h;
    co[7] = gp[7];
  }
}

extern "C" void kernel_launch(void* const* d_in, const int* in_sizes, int n_in,
                              void* d_out, int out_size, void* d_ws, size_t ws_size,
                              hipStream_t stream) {
  const float* box = (const float*)d_in[0];  // (B,N,7) f32
  const float* cls = (const float*)d_in[1];  // (B,N,3) f32
  const float* gt  = (const float*)d_in[2];  // (B,POST,8) f32
  float* out = (float*)d_out;                // 34816 f32, outputs concat in return order

  char* ws = (char*)d_ws;
  size_t off = 0;
  auto alloc = [&](size_t bytes) -> void* {
    void* p = ws + off;
    off += (bytes + 255) & ~(size_t)255;
    return p;
  };
  u32* hist   = (u32*)alloc((size_t)BB * 16384 * 4);  // 256 KB (first: covered by memset)
  u32* selctr = (u32*)alloc((size_t)BB * 4);          // zeroed by same memset
  u32* bstar  = (u32*)alloc((size_t)BB * 4);
  u32* sidx   = (u32*)alloc((size_t)BB * PRE * 4);
  float* gx1   = (float*)alloc((size_t)BB * PRE * 4);
  float* gx2   = (float*)alloc((size_t)BB * PRE * 4);
  float* gy1   = (float*)alloc((size_t)BB * PRE * 4);
  float* gy2   = (float*)alloc((size_t)BB * PRE * 4);
  float* garea = (float*)alloc((size_t)BB * PRE * 4);
  float* gsc   = (float*)alloc((size_t)BB * PRE * 4);
  u32* glab    = (u32*)alloc((size_t)BB * PRE * 4);
  u32* cnt     = (u32*)alloc((size_t)BB * PRE * 4);
  u64* hasadj  = (u64*)alloc((size_t)BB * 64 * 8);
  u32* adj     = (u32*)alloc((size_t)BB * PRE * CAP * 4);

  hipMemsetAsync(hist, 0, (size_t)BB * 16384 * 4 + 256, stream);  // hist + selctr

  hipLaunchKernelGGL(hist_kernel, dim3(BB * NN / 256), dim3(256), 0, stream, cls, hist);
  hipLaunchKernelGGL(bstar_kernel, dim3(BB), dim3(1024), 0, stream, hist, bstar);
  hipLaunchKernelGGL(select_kernel, dim3(BB), dim3(1024), 0, stream, cls, bstar, selctr, sidx);
  hipLaunchKernelGGL(geom_kernel, dim3(BB * PRE / 256), dim3(256), 0, stream,
                     box, cls, sidx, gx1, gx2, gy1, gy2, garea, gsc, glab, cnt, hasadj);
  hipLaunchKernelGGL(pairs_kernel, dim3(BB * 64 * 64), dim3(256), 0, stream,
                     gx1, gx2, gy1, gy2, garea, cnt, adj, hasadj);
  hipLaunchKernelGGL(nms_kernel, dim3(BB), dim3(256), 0, stream,
                     box, gt, sidx, gsc, glab, cnt, adj, hasadj, out);
}